// Round 3
// baseline (14.774 us; speedup 1.0000x reference)
//
#include <hip/hip_runtime.h>
#include <math.h>

#define TPB 256

#if __has_builtin(__builtin_amdgcn_rcpf)
__device__ __forceinline__ float frcp(float x) { return __builtin_amdgcn_rcpf(x); }
#else
__device__ __forceinline__ float frcp(float x) { return 1.0f / x; }
#endif

// HW sin/cos: v_sin_f32/v_cos_f32 take revolutions (x*2pi). Inputs a in
// [0, pi] -> rev in [0, 0.5]: no range reduction needed. ~few-ulp error,
// far below the 1.875e-2 pass threshold.
#define INV_2PI 0.15915494309189535f
#if __has_builtin(__builtin_amdgcn_sinf)
__device__ __forceinline__ float fsin(float a) { return __builtin_amdgcn_sinf(a * INV_2PI); }
__device__ __forceinline__ float fcos(float a) { return __builtin_amdgcn_cosf(a * INV_2PI); }
#else
__device__ __forceinline__ float fsin(float a) { return sinf(a); }
__device__ __forceinline__ float fcos(float a) { return cosf(a); }
#endif

__device__ __forceinline__ float fclamp(float x, float lo, float hi) {
    return fminf(fmaxf(x, lo), hi);   // -> v_med3_f32
}

// Rotated-box IoU, branch-free, registers-only clip math.
// Inputs staged via LDS so global loads are coalesced float4s instead of
// 20B-strided scalar gathers. LDS record reads: bank=(5t+c)%32, gcd(5,32)=1
// -> exactly 2 lanes/bank (free).
__global__ __launch_bounds__(TPB) void diff_iou_rotated_kernel(
    const float* __restrict__ box1, const float* __restrict__ box2,
    float* __restrict__ out, int n)
{
    const int t = threadIdx.x;
    const int g = blockIdx.x * TPB + t;

    __shared__ float s1[TPB * 5];
    __shared__ float s2[TPB * 5];

    // ---- Coalesced stage: 320 float4 per input per block. ----
    {
        const int total_f = n * 5;
        const int base_f  = blockIdx.x * (TPB * 5);
        #pragma unroll
        for (int k = 0; k < 2; ++k) {
            const int idx = t + k * TPB;          // float4 index within block slice
            if (idx < TPB * 5 / 4) {
                const int f = base_f + 4 * idx;
                if (f + 3 < total_f) {
                    ((float4*)s1)[idx] = ((const float4*)box1)[base_f / 4 + idx];
                    ((float4*)s2)[idx] = ((const float4*)box2)[base_f / 4 + idx];
                } else {
                    #pragma unroll
                    for (int j = 0; j < 4; ++j) {
                        const int ff = f + j;
                        s1[4 * idx + j] = (ff < total_f) ? box1[ff] : 0.0f;
                        s2[4 * idx + j] = (ff < total_f) ? box2[ff] : 0.0f;
                    }
                }
            }
        }
    }
    __syncthreads();
    if (g >= n) return;

    const float* p1 = &s1[t * 5];
    const float* p2 = &s2[t * 5];
    const float cx1 = p1[0], cy1 = p1[1], w1 = p1[2], h1 = p1[3], a1 = p1[4];
    const float cx2 = p2[0], cy2 = p2[1], w2 = p2[2], h2 = p2[3], a2 = p2[4];

    const float s1a = fsin(a1), c1a = fcos(a1);
    const float s2a = fsin(a2), c2a = fcos(a2);

    const float W = 0.5f * w1, H = 0.5f * h1;

    // box2 center in box1 frame (rotate by -a1), relative rotation a2-a1.
    const float dxc = cx2 - cx1, dyc = cy2 - cy1;
    const float lx =  c1a * dxc + s1a * dyc;
    const float ly = -s1a * dxc + c1a * dyc;
    const float cr = c2a * c1a + s2a * s1a;   // cos(a2-a1)
    const float sr = s2a * c1a - c2a * s1a;   // sin(a2-a1)

    // box2 corners in box1 frame (CCW).
    const float sx[4] = {0.5f, -0.5f, -0.5f, 0.5f};
    const float sy[4] = {0.5f, 0.5f, -0.5f, -0.5f};
    float vx[4], vy[4];
    #pragma unroll
    for (int i = 0; i < 4; ++i) {
        const float ox = sx[i] * w2, oy = sy[i] * h2;
        vx[i] = ox * cr - oy * sr + lx;
        vy[i] = ox * sr + oy * cr + ly;
    }

    // ---- Stage 1: clip against |x| <= W.  4 edges -> 12 emissions. ----
    // Each edge emits exactly 3 points (clamped P, then the <=2 slab-line
    // crossings in traversal order; invalid crossings duplicate the previous
    // emission). All degenerate emissions are collinear on a boundary line,
    // so the shoelace sum telescopes to the exact clipped area.
    float ux[12], uy[12];
    #pragma unroll
    for (int i = 0; i < 4; ++i) {
        const float px = vx[i],           py = vy[i];
        const float qx = vx[(i + 1) & 3], qy = vy[(i + 1) & 3];
        const float dx = qx - px, dy = qy - py;
        const float r  = frcp(dx);
        const float tl = (-W - px) * r;
        const float th = ( W - px) * r;
        const float tA = fminf(tl, th);
        const float tB = fmaxf(tl, th);
        const bool  vA = (tA > 0.0f) && (tA < 1.0f);
        const bool  vB = (tB > 0.0f) && (tB < 1.0f);

        const float e1x = fclamp(px, -W, W);
        const float e1y = py;
        const float xA = fclamp(px + tA * dx, -W, W);
        const float yA = py + tA * dy;
        const float eAx = vA ? xA : e1x;
        const float eAy = vA ? yA : e1y;
        const float xB = fclamp(px + tB * dx, -W, W);
        const float yB = py + tB * dy;
        const float eBx = vB ? xB : eAx;
        const float eBy = vB ? yB : eAy;

        ux[3 * i]     = e1x; uy[3 * i]     = e1y;
        ux[3 * i + 1] = eAx; uy[3 * i + 1] = eAy;
        ux[3 * i + 2] = eBx; uy[3 * i + 2] = eBy;
    }

    // ---- Stage 2: clip against |y| <= H, shoelace fused. ----
    float acc = 0.0f;
    float firstx = 0.0f, firsty = 0.0f, prevx = 0.0f, prevy = 0.0f;
    #pragma unroll
    for (int i = 0; i < 12; ++i) {
        const int j = (i + 1 == 12) ? 0 : i + 1;
        const float px = ux[i], py = uy[i];
        const float qx = ux[j], qy = uy[j];
        const float dx = qx - px, dy = qy - py;
        const float r  = frcp(dy);
        const float tl = (-H - py) * r;
        const float th = ( H - py) * r;
        const float tA = fminf(tl, th);
        const float tB = fmaxf(tl, th);
        const bool  vA = (tA > 0.0f) && (tA < 1.0f);
        const bool  vB = (tB > 0.0f) && (tB < 1.0f);

        const float e1x = px;
        const float e1y = fclamp(py, -H, H);
        const float yA = fclamp(py + tA * dy, -H, H);
        const float xA = px + tA * dx;
        const float eAx = vA ? xA : e1x;
        const float eAy = vA ? yA : e1y;
        const float yB = fclamp(py + tB * dy, -H, H);
        const float xB = px + tB * dx;
        const float eBx = vB ? xB : eAx;
        const float eBy = vB ? yB : eAy;

        if (i == 0) { firstx = e1x; firsty = e1y; }
        else        { acc += prevx * e1y - prevy * e1x; }
        acc += e1x * eAy - e1y * eAx;
        acc += eAx * eBy - eAy * eBx;
        prevx = eBx; prevy = eBy;
    }
    acc += prevx * firsty - prevy * firstx;

    const float inter = 0.5f * fabsf(acc);
    const float area1 = w1 * h1, area2 = w2 * h2;
    out[g] = inter * frcp(area1 + area2 - inter);
}

extern "C" void kernel_launch(void* const* d_in, const int* in_sizes, int n_in,
                              void* d_out, int out_size, void* d_ws, size_t ws_size,
                              hipStream_t stream) {
    const float* b1 = (const float*)d_in[0];
    const float* b2 = (const float*)d_in[1];
    float* out = (float*)d_out;
    const int n = in_sizes[0] / 5;   // (B,N,5) -> B*N pairs
    const int blocks = (n + TPB - 1) / TPB;
    hipLaunchKernelGGL(diff_iou_rotated_kernel, dim3(blocks), dim3(TPB), 0, stream,
                       b1, b2, out, n);
}

// Round 4
// 14.356 us; speedup vs baseline: 1.0291x; 1.0291x over previous
//
#include <hip/hip_runtime.h>
#include <math.h>

#define TPB 256

#if __has_builtin(__builtin_amdgcn_rcpf)
__device__ __forceinline__ float frcp(float x) { return __builtin_amdgcn_rcpf(x); }
#else
__device__ __forceinline__ float frcp(float x) { return 1.0f / x; }
#endif

// HW sin/cos take revolutions; a in [0,pi] -> rev in [0,0.5]: no reduction.
#define INV_2PI 0.15915494309189535f
#if __has_builtin(__builtin_amdgcn_sinf)
__device__ __forceinline__ float fsin(float a) { return __builtin_amdgcn_sinf(a * INV_2PI); }
__device__ __forceinline__ float fcos(float a) { return __builtin_amdgcn_cosf(a * INV_2PI); }
#else
__device__ __forceinline__ float fsin(float a) { return sinf(a); }
__device__ __forceinline__ float fcos(float a) { return cosf(a); }
#endif

__device__ __forceinline__ float fclamp(float x, float lo, float hi) {
    return fminf(fmaxf(x, lo), hi);   // -> v_med3_f32
}

// Rotated-box IoU, branch-free, fully streamed (no point arrays -> ~40 live
// VGPRs -> 8 waves/SIMD). Box1 is the axis-aligned slab |x|<=W,|y|<=H in its
// own frame. Stage 1 clips box2's quad against the x-slab emitting exactly 3
// points per edge (clamped P, then the <=2 slab crossings in traversal order;
// invalid crossings duplicate the previous emission — all degenerates are
// collinear on a boundary so the shoelace telescopes). Each stage-1 emission
// is fed immediately to the stage-2 (y-slab) edge processor with the fused
// shoelace, so nothing is materialized.
__global__ __launch_bounds__(TPB, 8) void diff_iou_rotated_kernel(
    const float* __restrict__ box1, const float* __restrict__ box2,
    float* __restrict__ out, int n)
{
    const int g = blockIdx.x * TPB + threadIdx.x;
    if (g >= n) return;

    const float* p1 = box1 + (size_t)g * 5;
    const float* p2 = box2 + (size_t)g * 5;
    const float cx1 = p1[0], cy1 = p1[1], w1 = p1[2], h1 = p1[3], a1 = p1[4];
    const float cx2 = p2[0], cy2 = p2[1], w2 = p2[2], h2 = p2[3], a2 = p2[4];

    const float s1a = fsin(a1), c1a = fcos(a1);
    const float s2a = fsin(a2), c2a = fcos(a2);

    const float W = 0.5f * w1, H = 0.5f * h1;
    const float sumarea = w1 * h1 + w2 * h2;

    // box2 center in box1 frame (rotate by -a1), relative rotation a2-a1.
    const float dxc = cx2 - cx1, dyc = cy2 - cy1;
    const float lx =  c1a * dxc + s1a * dyc;
    const float ly = -s1a * dxc + c1a * dyc;
    const float cr = c2a * c1a + s2a * s1a;   // cos(a2-a1)
    const float sr = s2a * c1a - c2a * s1a;   // sin(a2-a1)

    // box2 corners in box1 frame (CCW).
    const float sxc[4] = {0.5f, -0.5f, -0.5f, 0.5f};
    const float syc[4] = {0.5f, 0.5f, -0.5f, -0.5f};
    float vx[4], vy[4];
    #pragma unroll
    for (int i = 0; i < 4; ++i) {
        const float ox = sxc[i] * w2, oy = syc[i] * h2;
        vx[i] = ox * cr - oy * sr + lx;
        vy[i] = ox * sr + oy * cr + ly;
    }

    // Streaming state.
    float fUx = 0.f, fUy = 0.f;   // first stage-1 emission
    float pUx = 0.f, pUy = 0.f;   // prev  stage-1 emission
    float f2x = 0.f, f2y = 0.f;   // first stage-2 emission
    float p2x = 0.f, p2y = 0.f;   // prev  stage-2 emission
    float acc = 0.0f;

    // Stage-2 edge processor (y-slab clip + fused shoelace).
    auto stage2_edge = [&](float px, float py, float qx, float qy, bool first2) {
        const float dx = qx - px, dy = qy - py;
        const float r  = frcp(dy);
        const float tl = (-H - py) * r;
        const float th = ( H - py) * r;
        const float tA = fminf(tl, th);
        const float tB = fmaxf(tl, th);
        const bool  vA = (tA > 0.0f) && (tA < 1.0f);
        const bool  vB = (tB > 0.0f) && (tB < 1.0f);

        const float e1x = px;
        const float e1y = fclamp(py, -H, H);
        const float yA = fclamp(py + tA * dy, -H, H);
        const float xA = px + tA * dx;
        const float eAx = vA ? xA : e1x;
        const float eAy = vA ? yA : e1y;
        const float yB = fclamp(py + tB * dy, -H, H);
        const float xB = px + tB * dx;
        const float eBx = vB ? xB : eAx;
        const float eBy = vB ? yB : eAy;

        if (first2) { f2x = e1x; f2y = e1y; }
        else        { acc += p2x * e1y - p2y * e1x; }
        acc += e1x * eAy - e1y * eAx;
        acc += eAx * eBy - eAy * eBx;
        p2x = eBx; p2y = eBy;
    };

    // Feed one stage-1 emission (global point index k = 0..11).
    auto feedU = [&](float x, float y, int k) {
        if (k == 0) { fUx = x; fUy = y; }
        else        { stage2_edge(pUx, pUy, x, y, /*first2=*/(k == 1)); }
        pUx = x; pUy = y;
    };

    // Stage 1: clip box2 quad against |x| <= W, 3 emissions per edge.
    #pragma unroll
    for (int i = 0; i < 4; ++i) {
        const float px = vx[i],           py = vy[i];
        const float qx = vx[(i + 1) & 3], qy = vy[(i + 1) & 3];
        const float dx = qx - px, dy = qy - py;
        const float r  = frcp(dx);
        const float tl = (-W - px) * r;
        const float th = ( W - px) * r;
        const float tA = fminf(tl, th);
        const float tB = fmaxf(tl, th);
        const bool  vA = (tA > 0.0f) && (tA < 1.0f);
        const bool  vB = (tB > 0.0f) && (tB < 1.0f);

        const float e1x = fclamp(px, -W, W);
        const float e1y = py;
        const float xA = fclamp(px + tA * dx, -W, W);
        const float yA = py + tA * dy;
        const float eAx = vA ? xA : e1x;
        const float eAy = vA ? yA : e1y;
        const float xB = fclamp(px + tB * dx, -W, W);
        const float yB = py + tB * dy;
        const float eBx = vB ? xB : eAx;
        const float eBy = vB ? yB : eAy;

        feedU(e1x, e1y, 3 * i);
        feedU(eAx, eAy, 3 * i + 1);
        feedU(eBx, eBy, 3 * i + 2);
    }
    // Wrap stage-1 polygon (u11 -> u0), then close stage-2 ring.
    stage2_edge(pUx, pUy, fUx, fUy, false);
    acc += p2x * f2y - p2y * f2x;

    const float inter = 0.5f * fabsf(acc);
    out[g] = inter * frcp(sumarea - inter);
}

extern "C" void kernel_launch(void* const* d_in, const int* in_sizes, int n_in,
                              void* d_out, int out_size, void* d_ws, size_t ws_size,
                              hipStream_t stream) {
    const float* b1 = (const float*)d_in[0];
    const float* b2 = (const float*)d_in[1];
    float* out = (float*)d_out;
    const int n = in_sizes[0] / 5;   // (B,N,5) -> B*N pairs
    const int blocks = (n + TPB - 1) / TPB;
    hipLaunchKernelGGL(diff_iou_rotated_kernel, dim3(blocks), dim3(TPB), 0, stream,
                       b1, b2, out, n);
}

// Round 5
// 9.914 us; speedup vs baseline: 1.4903x; 1.4481x over previous
//
#include <hip/hip_runtime.h>
#include <math.h>

#define TPB 256

__device__ __forceinline__ float frcp(float x) {
#if __has_builtin(__builtin_amdgcn_rcpf)
    return __builtin_amdgcn_rcpf(x);
#else
    return 1.0f / x;
#endif
}

// HW sin/cos take revolutions; a in [0,pi] -> rev in [0,0.5]: no reduction.
#define INV_2PI 0.15915494309189535f
__device__ __forceinline__ float fsin(float a) {
#if __has_builtin(__builtin_amdgcn_sinf)
    return __builtin_amdgcn_sinf(a * INV_2PI);
#else
    return sinf(a);
#endif
}
__device__ __forceinline__ float fcos(float a) {
#if __has_builtin(__builtin_amdgcn_cosf)
    return __builtin_amdgcn_cosf(a * INV_2PI);
#else
    return cosf(a);
#endif
}

__device__ __forceinline__ float fclamp(float x, float lo, float hi) {
    return fminf(fmaxf(x, lo), hi);   // -> v_med3_f32
}

// Rotated-box IoU via clamped Green's theorem.
//
// In box1's frame, box1 = [-W,W] x [-H,H]. For the CCW quad P = box2:
//   Area(P ∩ box1) = ∮_{∂P} clamp(x,-W,W) d(clamp(y,-H,H))
// (Green: d/dx clamp(x) = 1 inside the x-slab, 0 outside; dclamp(y) kills
// edge portions outside the y-slab.) Per linear edge p->q the integral is
// closed-form: restrict t to the y-band interval [ta,tb], split it at the
// x-band crossings [sa,sb] in [ta,tb]; the three sub-segments contribute
//   clampx(x(ta))*(y(sa)-y(ta)) + x((sa+sb)/2)*(y(sb)-y(sa))
//                               + clampx(x(tb))*(y(tb)-y(sb)).
// ~38 VALU per edge, 4 edges total — no polygon materialization at all.
// Degenerate dx/dy==0 guarded by selects; contributions then collapse to 0
// because the y-differences use the true dy.
__global__ __launch_bounds__(TPB, 8) void diff_iou_rotated_kernel(
    const float* __restrict__ box1, const float* __restrict__ box2,
    float* __restrict__ out, int n)
{
    const int g = blockIdx.x * TPB + threadIdx.x;
    if (g >= n) return;

    const float* p1 = box1 + (size_t)g * 5;
    const float* p2 = box2 + (size_t)g * 5;
    const float cx1 = p1[0], cy1 = p1[1], w1 = p1[2], h1 = p1[3], a1 = p1[4];
    const float cx2 = p2[0], cy2 = p2[1], w2 = p2[2], h2 = p2[3], a2 = p2[4];

    const float s1a = fsin(a1), c1a = fcos(a1);
    const float s2a = fsin(a2), c2a = fcos(a2);

    const float W = 0.5f * w1, H = 0.5f * h1;
    const float sumarea = w1 * h1 + w2 * h2;

    // box2 center in box1 frame (rotate by -a1), relative rotation a2-a1.
    const float dxc = cx2 - cx1, dyc = cy2 - cy1;
    const float lx =  c1a * dxc + s1a * dyc;
    const float ly = -s1a * dxc + c1a * dyc;
    const float cr = c2a * c1a + s2a * s1a;   // cos(a2-a1)
    const float sr = s2a * c1a - c2a * s1a;   // sin(a2-a1)

    // box2 corners in box1 frame, CCW (positive shoelace orientation).
    const float sxc[4] = {0.5f, -0.5f, -0.5f, 0.5f};
    const float syc[4] = {0.5f, 0.5f, -0.5f, -0.5f};
    float vx[4], vy[4];
    #pragma unroll
    for (int i = 0; i < 4; ++i) {
        const float ox = sxc[i] * w2, oy = syc[i] * h2;
        vx[i] = ox * cr - oy * sr + lx;
        vy[i] = ox * sr + oy * cr + ly;
    }

    float acc = 0.0f;
    #pragma unroll
    for (int i = 0; i < 4; ++i) {
        const float px = vx[i],           py = vy[i];
        const float qx = vx[(i + 1) & 3], qy = vy[(i + 1) & 3];
        const float dx = qx - px, dy = qy - py;
        const float dys = (dy == 0.0f) ? 1e-30f : dy;
        const float dxs = (dx == 0.0f) ? 1e-30f : dx;

        // y-band param interval [ta,tb] ⊆ [0,1].
        const float r  = frcp(dys);
        const float t0 = (-H - py) * r;
        const float t1 = ( H - py) * r;
        const float ta = fclamp(fminf(t0, t1), 0.0f, 1.0f);
        const float tb = fclamp(fmaxf(t0, t1), 0.0f, 1.0f);

        // x-band crossings clamped into [ta,tb].
        const float rx = frcp(dxs);
        const float s0 = (-W - px) * rx;
        const float s1 = ( W - px) * rx;
        const float sa = fclamp(fminf(s0, s1), ta, tb);
        const float sb = fclamp(fmaxf(s0, s1), ta, tb);

        const float ya  = fmaf(ta, dy, py);
        const float ysa = fmaf(sa, dy, py);
        const float ysb = fmaf(sb, dy, py);
        const float yb  = fmaf(tb, dy, py);

        const float xac = fclamp(fmaf(ta, dx, px), -W, W);
        const float xbc = fclamp(fmaf(tb, dx, px), -W, W);
        const float xm  = fmaf(0.5f * (sa + sb), dx, px);

        acc = fmaf(xac, ysa - ya, acc);
        acc = fmaf(xm,  ysb - ysa, acc);
        acc = fmaf(xbc, yb - ysb, acc);
    }

    const float inter = fabsf(acc);
    out[g] = inter * frcp(sumarea - inter);
}

extern "C" void kernel_launch(void* const* d_in, const int* in_sizes, int n_in,
                              void* d_out, int out_size, void* d_ws, size_t ws_size,
                              hipStream_t stream) {
    const float* b1 = (const float*)d_in[0];
    const float* b2 = (const float*)d_in[1];
    float* out = (float*)d_out;
    const int n = in_sizes[0] / 5;   // (B,N,5) -> B*N pairs
    const int blocks = (n + TPB - 1) / TPB;
    hipLaunchKernelGGL(diff_iou_rotated_kernel, dim3(blocks), dim3(TPB), 0, stream,
                       b1, b2, out, n);
}

// Round 6
// 9.722 us; speedup vs baseline: 1.5197x; 1.0197x over previous
//
#include <hip/hip_runtime.h>
#include <math.h>

#define TPB 256

__device__ __forceinline__ float frcp(float x) {
#if __has_builtin(__builtin_amdgcn_rcpf)
    return __builtin_amdgcn_rcpf(x);
#else
    return 1.0f / x;
#endif
}

// HW sin/cos take revolutions; a in [0,pi] -> rev in [0,0.5]: no reduction.
#define INV_2PI 0.15915494309189535f
__device__ __forceinline__ float fsin(float a) {
#if __has_builtin(__builtin_amdgcn_sinf)
    return __builtin_amdgcn_sinf(a * INV_2PI);
#else
    return sinf(a);
#endif
}
__device__ __forceinline__ float fcos(float a) {
#if __has_builtin(__builtin_amdgcn_cosf)
    return __builtin_amdgcn_cosf(a * INV_2PI);
#else
    return cosf(a);
#endif
}

__device__ __forceinline__ float fclamp(float x, float lo, float hi) {
    return fminf(fmaxf(x, lo), hi);   // -> v_med3_f32
}

// One edge's contribution to the clamped Green integral
//   Area(P ∩ [-W,W]x[-H,H]) = ∮ clamp(x,-W,W) d(clamp(y,-H,H))
// rx, ry are (guarded) reciprocals of dx, dy; guard sign is irrelevant since
// min/max reorders the crossings afterwards.
__device__ __forceinline__ float edge_int(float px, float py, float dx, float dy,
                                          float rx, float ry, float W, float H) {
    const float t0 = (-H - py) * ry;
    const float t1 = ( H - py) * ry;
    const float ta = fclamp(fminf(t0, t1), 0.0f, 1.0f);
    const float tb = fclamp(fmaxf(t0, t1), 0.0f, 1.0f);

    const float s0 = (-W - px) * rx;
    const float s1 = ( W - px) * rx;
    const float sa = fclamp(fminf(s0, s1), ta, tb);
    const float sb = fclamp(fmaxf(s0, s1), ta, tb);

    const float ya  = fmaf(ta, dy, py);
    const float ysa = fmaf(sa, dy, py);
    const float ysb = fmaf(sb, dy, py);
    const float yb  = fmaf(tb, dy, py);

    const float xac = fclamp(fmaf(ta, dx, px), -W, W);
    const float xbc = fclamp(fmaf(tb, dx, px), -W, W);
    const float xm  = fmaf(0.5f * (sa + sb), dx, px);

    return xac * (ysa - ya) + xm * (ysb - ysa) + xbc * (yb - ysb);
}

__device__ __forceinline__ float iou_pair(float cx1, float cy1, float w1, float h1, float a1,
                                          float cx2, float cy2, float w2, float h2, float a2) {
    const float s1a = fsin(a1), c1a = fcos(a1);
    const float s2a = fsin(a2), c2a = fcos(a2);

    const float W = 0.5f * w1, H = 0.5f * h1;

    // box2 center in box1 frame, relative rotation a2-a1.
    const float dxc = cx2 - cx1, dyc = cy2 - cy1;
    const float lx =  c1a * dxc + s1a * dyc;
    const float ly = -s1a * dxc + c1a * dyc;
    const float cr = c2a * c1a + s2a * s1a;
    const float sr = s2a * c1a - c2a * s1a;

    // Rectangle axes: u = w2*(cr,sr), v = h2*(-sr,cr). CCW corners l ± u/2 ± v/2.
    const float ux = w2 * cr, uy = w2 * sr;
    const float vx = -h2 * sr, vy = h2 * cr;
    const float hux = 0.5f * ux, huy = 0.5f * uy;
    const float hvx = 0.5f * vx, hvy = 0.5f * vy;
    const float c0x = lx + hux + hvx, c0y = ly + huy + hvy;
    const float c1x = lx - hux + hvx, c1y = ly - huy + hvy;
    const float c2x = lx - hux - hvx, c2y = ly - huy - hvy;
    const float c3x = lx + hux - hvx, c3y = ly + huy - hvy;

    // Edge deltas are -u, -v, +u, +v: 4 guarded rcps shared across edges.
    const float rux = frcp(ux == 0.0f ? 1e-30f : ux);
    const float ruy = frcp(uy == 0.0f ? 1e-30f : uy);
    const float rvx = frcp(vx == 0.0f ? 1e-30f : vx);
    const float rvy = frcp(vy == 0.0f ? 1e-30f : vy);

    float acc;
    acc  = edge_int(c0x, c0y, -ux, -uy, -rux, -ruy, W, H);
    acc += edge_int(c1x, c1y, -vx, -vy, -rvx, -rvy, W, H);
    acc += edge_int(c2x, c2y,  ux,  uy,  rux,  ruy, W, H);
    acc += edge_int(c3x, c3y,  vx,  vy,  rvx,  rvy, W, H);

    const float inter = fabsf(acc);
    const float sumarea = w1 * h1 + w2 * h2;
    return inter * frcp(sumarea - inter);
}

// Two adjacent box pairs per thread: halves wave count, doubles ILP, and
// turns 20 scalar loads into 10 dwordx2 loads (offset 40t bytes, 8-aligned)
// plus one float2 store.
__global__ __launch_bounds__(TPB, 8) void diff_iou_rotated_kernel(
    const float* __restrict__ box1, const float* __restrict__ box2,
    float* __restrict__ out, int n)
{
    const int t = blockIdx.x * TPB + threadIdx.x;
    const int i0 = 2 * t;
    if (i0 >= n) return;

    if (i0 + 1 < n) {
        const float2* p1 = (const float2*)(box1 + (size_t)i0 * 5);
        const float2* p2 = (const float2*)(box2 + (size_t)i0 * 5);
        const float2 A0 = p1[0], A1 = p1[1], A2 = p1[2], A3 = p1[3], A4 = p1[4];
        const float2 B0 = p2[0], B1 = p2[1], B2 = p2[2], B3 = p2[3], B4 = p2[4];

        const float r0 = iou_pair(A0.x, A0.y, A1.x, A1.y, A2.x,
                                  B0.x, B0.y, B1.x, B1.y, B2.x);
        const float r1 = iou_pair(A2.y, A3.x, A3.y, A4.x, A4.y,
                                  B2.y, B3.x, B3.y, B4.x, B4.y);
        *(float2*)(out + i0) = make_float2(r0, r1);
    } else {
        const float* p1 = box1 + (size_t)i0 * 5;
        const float* p2 = box2 + (size_t)i0 * 5;
        out[i0] = iou_pair(p1[0], p1[1], p1[2], p1[3], p1[4],
                           p2[0], p2[1], p2[2], p2[3], p2[4]);
    }
}

extern "C" void kernel_launch(void* const* d_in, const int* in_sizes, int n_in,
                              void* d_out, int out_size, void* d_ws, size_t ws_size,
                              hipStream_t stream) {
    const float* b1 = (const float*)d_in[0];
    const float* b2 = (const float*)d_in[1];
    float* out = (float*)d_out;
    const int n = in_sizes[0] / 5;   // (B,N,5) -> B*N pairs
    const int nthreads = (n + 1) / 2;
    const int blocks = (nthreads + TPB - 1) / TPB;
    hipLaunchKernelGGL(diff_iou_rotated_kernel, dim3(blocks), dim3(TPB), 0, stream,
                       b1, b2, out, n);
}